// Round 1
// baseline (432.975 us; speedup 1.0000x reference)
//
#include <hip/hip_runtime.h>
#include <hip/hip_bf16.h>

typedef __attribute__((ext_vector_type(8))) short short8;
typedef __attribute__((ext_vector_type(4))) float f32x4;
typedef unsigned short u16;

// sizes
#define B_      32
#define IC_     128
#define OC_     256
#define HD_     768
#define WD_     384
#define CTX_    256

static __device__ __forceinline__ u16 f2bf(float f) {
    union { float f; unsigned u; } x; x.f = f;
    unsigned r = x.u + 0x7FFFu + ((x.u >> 16) & 1u);
    return (u16)(r >> 16);
}

// ---------------------------------------------------------------- K1: mobius
// sc[b, s*16+q] = sum_r w_re[b,s,r]*A_re[s,r,q] + w_im[b,s,r]*A_im[s,r,q]
__global__ __launch_bounds__(256) void k1_mobius(
    const float* __restrict__ ctx, const float* __restrict__ Wm,
    const float* __restrict__ z, const float* __restrict__ Are,
    const float* __restrict__ Aim, float* __restrict__ sc) {
    int b = blockIdx.x, t = threadIdx.x;
    __shared__ float lctx[CTX_];
    __shared__ float lwre[256], lwim[256];
    lctx[t] = ctx[b * CTX_ + t];
    __syncthreads();
    // t = s*16 + r
    float m0=0,m1=0,m2=0,m3=0,m4=0,m5=0,m6=0,m7=0;
    const float* wp = Wm + (size_t)t * 8;   // + c*2048
    for (int c = 0; c < CTX_; ++c) {
        const float* w = wp + (size_t)c * 2048;
        float cv = lctx[c];
        m0 += cv*w[0]; m1 += cv*w[1]; m2 += cv*w[2]; m3 += cv*w[3];
        m4 += cv*w[4]; m5 += cv*w[5]; m6 += cv*w[6]; m7 += cv*w[7];
    }
    float zre = z[t*2], zim = z[t*2+1];
    float nre = m0*zre - m1*zim + m2;
    float nim = m0*zim + m1*zre + m3;
    float dre = m4*zre - m5*zim + m6;
    float dim_ = m4*zim + m5*zre + m7;
    float den2 = dre*dre + dim_*dim_ + 1e-3f;
    lwre[t] = (nre*dre + nim*dim_) / den2;
    lwim[t] = (nim*dre - nre*dim_) / den2;
    __syncthreads();
    int s = t >> 4, q = t & 15;
    float acc = 0.f;
    #pragma unroll
    for (int r2 = 0; r2 < 16; ++r2) {
        int sr = s*16 + r2;
        acc += lwre[sr]*Are[sr*16 + q] + lwim[sr]*Aim[sr*16 + q];
    }
    sc[b*256 + t] = acc;
}

// ---------------------------------------------------- K2: padded bf16 image
// xp[b][yy][xx][i]  (channel-last), yy,xx in [0,66), border = pad_val
__global__ __launch_bounds__(256) void k2_pad(
    const float* __restrict__ x, const float* __restrict__ padv,
    const float* __restrict__ offv, u16* __restrict__ xp) {
    int yy = blockIdx.x, b = blockIdx.y, t = threadIdx.x;
    __shared__ u16 lds[64 * 136];  // [xx][i], stride 136 (16B-aligned rows)
    float off = offv[0];
    u16 pb = f2bf(padv[0]);
    unsigned pp = (unsigned)pb | ((unsigned)pb << 16);
    int4 padvec = make_int4((int)pp, (int)pp, (int)pp, (int)pp);
    u16* row = xp + (size_t)(b * 66 + yy) * (66 * 128);
    if (yy == 0 || yy == 65) {
        for (int c = t; c < 1056; c += 256)
            *(int4*)(row + c * 8) = padvec;
        return;
    }
    int y = yy - 1;
    const float* xin = x + (size_t)b * 524288 + (size_t)y * 64; // + i*4096 + xx
    for (int id = t; id < 8192; id += 256) {
        int i = id >> 6, xx = id & 63;
        lds[xx * 136 + i] = f2bf(xin[(size_t)i * 4096 + xx] + off);
    }
    __syncthreads();
    for (int c = t; c < 1056; c += 256) {
        int e = c * 8, xx = e >> 7, i0 = e & 127;
        int4 v;
        if (xx == 0 || xx == 65) v = padvec;
        else v = *(const int4*)(lds + (xx - 1) * 136 + i0);
        *(int4*)(row + e) = v;
    }
}

// ------------------------------------------------- K3a: U_cat[h][k] bf16
// k = s*16+q ; U layout [S][HD][Q]
__global__ __launch_bounds__(256) void k3a_ucat(
    const float* __restrict__ U, u16* __restrict__ Ucat) {
    int id = blockIdx.x * 256 + threadIdx.x;       // < 768*256
    int h = id >> 8, k = id & 255;
    int s = k >> 4, q = k & 15;
    Ucat[id] = f2bf(U[((size_t)s * HD_ + h) * 16 + q]);
}

// ------------------------------------------- K3b: Vb_t[b][w][k] bf16 scaled
__global__ __launch_bounds__(256) void k3b_vbt(
    const float* __restrict__ V, const float* __restrict__ sc,
    u16* __restrict__ Vbt) {
    int id = blockIdx.x * 256 + threadIdx.x;       // < 1,572,864
    int e0 = id * 2;
    int b = e0 / 98304;                             // 384*256
    int rem = e0 - b * 98304;
    int w = rem >> 8, k0 = rem & 255;
    int s0 = k0 >> 4, q0 = k0 & 15;
    int k1 = k0 + 1, s1 = k1 >> 4, q1 = k1 & 15;
    float v0 = V[((size_t)s0 * 16 + q0) * WD_ + w] * sc[b * 256 + k0];
    float v1 = V[((size_t)s1 * 16 + q1) * WD_ + w] * sc[b * 256 + k1];
    unsigned pack = (unsigned)f2bf(v0) | ((unsigned)f2bf(v1) << 16);
    *(unsigned*)(Vbt + e0) = pack;
}

// ---------------------- K4: dw GEMM (MFMA) + bias + gather-scatter epilogue
// dw[b] = Ucat[768,256] @ Vbt[b][·,·]^T-ish  -> conv_w[b][kh][kw][o][i] bf16
__global__ __launch_bounds__(256, 2) void k4_dw(
    const u16* __restrict__ Ucat, const u16* __restrict__ Vbt,
    const float* __restrict__ bias_dw, u16* __restrict__ cw) {
    int nt = blockIdx.x, mt = blockIdx.y, b = blockIdx.z;
    int t = threadIdx.x;
    __shared__ __align__(16) u16 Al[128 * 40];
    __shared__ __align__(16) u16 Bl[128 * 40];
    int h0 = mt * 128, w0 = nt * 128;
    f32x4 acc[4][4] = {};
    int wid = t >> 6, l = t & 63;
    int wm = wid >> 1, wn = wid & 1;
    int lr = l & 15, lg = l >> 4;
    for (int kc = 0; kc < 8; ++kc) {
        __syncthreads();
        #pragma unroll
        for (int it = 0; it < 2; ++it) {
            int cid = t + it * 256;
            int g = cid & 3, hh = cid >> 2;
            int4 v = *(const int4*)(Ucat + (size_t)(h0 + hh) * 256 + kc * 32 + g * 8);
            *(int4*)(Al + hh * 40 + g * 8) = v;
        }
        #pragma unroll
        for (int it = 0; it < 2; ++it) {
            int cid = t + it * 256;
            int g = cid & 3, ww = cid >> 2;
            int4 v = *(const int4*)(Vbt + (size_t)b * 98304 + (size_t)(w0 + ww) * 256 + kc * 32 + g * 8);
            *(int4*)(Bl + ww * 40 + g * 8) = v;
        }
        __syncthreads();
        short8 a[4];
        #pragma unroll
        for (int fm = 0; fm < 4; ++fm)
            a[fm] = *(const short8*)(Al + (wm * 64 + fm * 16 + lr) * 40 + lg * 8);
        #pragma unroll
        for (int fn = 0; fn < 4; ++fn) {
            short8 bb = *(const short8*)(Bl + (wn * 64 + fn * 16 + lr) * 40 + lg * 8);
            #pragma unroll
            for (int fm = 0; fm < 4; ++fm)
                acc[fm][fn] = __builtin_amdgcn_mfma_f32_16x16x32_bf16(a[fm], bb, acc[fm][fn], 0, 0, 0);
        }
    }
    // epilogue: dw(h,w) + bias -> conv_w[b][kh][kw][o][i]
    #pragma unroll
    for (int fm = 0; fm < 4; ++fm)
        #pragma unroll
        for (int fn = 0; fn < 4; ++fn)
            #pragma unroll
            for (int j = 0; j < 4; ++j) {
                int h = h0 + wm * 64 + fm * 16 + lg * 4 + j;
                int w = w0 + wn * 64 + fn * 16 + lr;
                float val = acc[fm][fn][j] + bias_dw[h * 384 + w];
                int bi = (int)((unsigned)h / 3u); int kh = h - bi * 3;
                int bj = (int)((unsigned)w / 3u); int kw = w - bj * 3;
                int lin = bi * 128 + bj;
                int o = lin & 255, i = lin >> 8;
                cw[(((size_t)(b * 9 + kh * 3 + kw) * 256 + o) * 128) + i] = f2bf(val);
            }
}

// --------------------------------------------- K6: implicit-GEMM conv (MFMA)
// block = (pixel-tile nt: 2 rows, sample b); BM=256 (all o), BN=128 pixels
__global__ __launch_bounds__(256, 2) void k6_conv(
    const u16* __restrict__ xp, const u16* __restrict__ cw,
    const float* __restrict__ bias_conv, float* __restrict__ out) {
    int nt = blockIdx.x, b = blockIdx.y, t = threadIdx.x;
    int y0 = nt * 2;
    __shared__ __align__(16) u16 Xl[4 * 66 * 40];   // [row][col][ch-slot 40]
    __shared__ __align__(16) u16 Wl[256 * 40];      // [o][ch-slot 40]
    f32x4 acc[4][8] = {};
    int wid = t >> 6, l = t & 63, lr = l & 15, lg = l >> 4;
    const u16* xpb = xp + (size_t)b * 66 * 66 * 128;
    const u16* cwb = cw + (size_t)b * 9 * 256 * 128;
    for (int ic = 0; ic < 4; ++ic) {
        __syncthreads();   // protect Xl from previous chunk's readers
        #pragma unroll
        for (int it = 0; it < 5; ++it) {
            int cid = t + it * 256;
            if (cid < 1056) {
                int row = cid / 264, rem = cid - row * 264;
                int col = rem >> 2, g = rem & 3;
                int4 v = *(const int4*)(xpb + ((size_t)(y0 + row) * 66 + col) * 128 + ic * 32 + g * 8);
                *(int4*)(Xl + (row * 66 + col) * 40 + g * 8) = v;
            }
        }
        for (int khkw = 0; khkw < 9; ++khkw) {
            __syncthreads();   // waves done with previous Wl (and Xl staged)
            #pragma unroll
            for (int it = 0; it < 4; ++it) {
                int cid = t + it * 256;
                int g = cid & 3, o = cid >> 2;
                int4 v = *(const int4*)(cwb + ((size_t)khkw * 256 + o) * 128 + ic * 32 + g * 8);
                *(int4*)(Wl + o * 40 + g * 8) = v;
            }
            __syncthreads();
            int kh = (int)((unsigned)khkw / 3u);
            int kw = khkw - kh * 3;
            short8 a[4];
            #pragma unroll
            for (int fm = 0; fm < 4; ++fm)
                a[fm] = *(const short8*)(Wl + (wid * 64 + fm * 16 + lr) * 40 + lg * 8);
            #pragma unroll
            for (int fn = 0; fn < 8; ++fn) {
                int rowsel = fn >> 2, xq = fn & 3;
                int r = rowsel + kh, c = xq * 16 + lr + kw;
                short8 bb = *(const short8*)(Xl + (r * 66 + c) * 40 + lg * 8);
                #pragma unroll
                for (int fm = 0; fm < 4; ++fm)
                    acc[fm][fn] = __builtin_amdgcn_mfma_f32_16x16x32_bf16(a[fm], bb, acc[fm][fn], 0, 0, 0);
            }
        }
    }
    // epilogue: out[b][o][y][x] = acc + bias_conv[o]
    #pragma unroll
    for (int fm = 0; fm < 4; ++fm)
        #pragma unroll
        for (int fn = 0; fn < 8; ++fn) {
            int y = y0 + (fn >> 2);
            int xb = (fn & 3) * 16 + lr;
            #pragma unroll
            for (int j = 0; j < 4; ++j) {
                int o = wid * 64 + fm * 16 + lg * 4 + j;
                out[(((size_t)b * 256 + o) * 64 + y) * 64 + xb] = acc[fm][fn][j] + bias_conv[o];
            }
        }
}

extern "C" void kernel_launch(void* const* d_in, const int* in_sizes, int n_in,
                              void* d_out, int out_size, void* d_ws, size_t ws_size,
                              hipStream_t stream) {
    const float* x     = (const float*)d_in[0];
    const float* ctx   = (const float*)d_in[1];
    const float* Wm    = (const float*)d_in[2];
    const float* z     = (const float*)d_in[3];
    const float* Are   = (const float*)d_in[4];
    const float* Aim   = (const float*)d_in[5];
    const float* U     = (const float*)d_in[6];
    const float* V     = (const float*)d_in[7];
    const float* bdw   = (const float*)d_in[8];
    const float* bconv = (const float*)d_in[9];
    const float* padv  = (const float*)d_in[10];
    const float* offv  = (const float*)d_in[11];
    // d_in[12] = dw_index: mapping computed in closed form in k4's epilogue.
    float* out = (float*)d_out;
    char* ws = (char*)d_ws;

    u16*   xp   = (u16*)(ws);                 // 32*66*66*128*2 = 35,684,352 B
    u16*   Vbt  = (u16*)(ws + 35684352);      // 32*384*256*2   =  6,291,456 B
    u16*   Ucat = (u16*)(ws + 41975808);      // 768*256*2      =    393,216 B
    float* sc   = (float*)(ws + 42369024);    // 32*256*4       =     32,768 B
    u16*   cw   = (u16*)(ws + 42401792);      // 32*9*256*128*2 = 18,874,368 B
                                              // total ~58.5 MB of d_ws

    k1_mobius<<<32, 256, 0, stream>>>(ctx, Wm, z, Are, Aim, sc);
    k2_pad<<<dim3(66, 32), 256, 0, stream>>>(x, padv, offv, xp);
    k3a_ucat<<<768, 256, 0, stream>>>(U, Ucat);
    k3b_vbt<<<6144, 256, 0, stream>>>(V, sc, Vbt);
    k4_dw<<<dim3(3, 6, 32), 256, 0, stream>>>(Ucat, Vbt, bdw, cw);
    k6_conv<<<dim3(32, 32), 256, 0, stream>>>(xp, cw, bconv, out);
}

// Round 2
// 368.333 us; speedup vs baseline: 1.1755x; 1.1755x over previous
//
#include <hip/hip_runtime.h>
#include <hip/hip_bf16.h>

typedef __attribute__((ext_vector_type(8))) short short8;
typedef __attribute__((ext_vector_type(4))) float f32x4;
typedef unsigned short u16;

#define B_      32
#define IC_     128
#define OC_     256
#define HD_     768
#define WD_     384
#define CTX_    256

static __device__ __forceinline__ u16 f2bf(float f) {
    union { float f; unsigned u; } x; x.f = f;
    unsigned r = x.u + 0x7FFFu + ((x.u >> 16) & 1u);
    return (u16)(r >> 16);
}

// ---------------------------------------------------------------- K1: mobius
__global__ __launch_bounds__(256) void k1_mobius(
    const float* __restrict__ ctx, const float* __restrict__ Wm,
    const float* __restrict__ z, const float* __restrict__ Are,
    const float* __restrict__ Aim, float* __restrict__ sc) {
    int b = blockIdx.x, t = threadIdx.x;
    __shared__ float lctx[CTX_];
    __shared__ float lwre[256], lwim[256];
    lctx[t] = ctx[b * CTX_ + t];
    __syncthreads();
    float m0=0,m1=0,m2=0,m3=0,m4=0,m5=0,m6=0,m7=0;
    const float* wp = Wm + (size_t)t * 8;
    for (int c = 0; c < CTX_; ++c) {
        const float* w = wp + (size_t)c * 2048;
        float cv = lctx[c];
        m0 += cv*w[0]; m1 += cv*w[1]; m2 += cv*w[2]; m3 += cv*w[3];
        m4 += cv*w[4]; m5 += cv*w[5]; m6 += cv*w[6]; m7 += cv*w[7];
    }
    float zre = z[t*2], zim = z[t*2+1];
    float nre = m0*zre - m1*zim + m2;
    float nim = m0*zim + m1*zre + m3;
    float dre = m4*zre - m5*zim + m6;
    float dim_ = m4*zim + m5*zre + m7;
    float den2 = dre*dre + dim_*dim_ + 1e-3f;
    lwre[t] = (nre*dre + nim*dim_) / den2;
    lwim[t] = (nim*dre - nre*dim_) / den2;
    __syncthreads();
    int s = t >> 4, q = t & 15;
    float acc = 0.f;
    #pragma unroll
    for (int r2 = 0; r2 < 16; ++r2) {
        int sr = s*16 + r2;
        acc += lwre[sr]*Are[sr*16 + q] + lwim[sr]*Aim[sr*16 + q];
    }
    sc[b*256 + t] = acc;
}

// ---------------------------------------------------- K2: padded bf16 image
// xp[b][yy][xx][i]  (channel-last), yy,xx in [0,66), border = pad_val
__global__ __launch_bounds__(256) void k2_pad(
    const float* __restrict__ x, const float* __restrict__ padv,
    const float* __restrict__ offv, u16* __restrict__ xp) {
    int yy = blockIdx.x, b = blockIdx.y, t = threadIdx.x;
    __shared__ u16 lds[64 * 136];
    float off = offv[0];
    u16 pb = f2bf(padv[0]);
    unsigned pp = (unsigned)pb | ((unsigned)pb << 16);
    int4 padvec = make_int4((int)pp, (int)pp, (int)pp, (int)pp);
    u16* row = xp + (size_t)(b * 66 + yy) * (66 * 128);
    if (yy == 0 || yy == 65) {
        for (int c = t; c < 1056; c += 256)
            *(int4*)(row + c * 8) = padvec;
        return;
    }
    int y = yy - 1;
    const float* xin = x + (size_t)b * 524288 + (size_t)y * 64;
    for (int id = t; id < 8192; id += 256) {
        int i = id >> 6, xx = id & 63;
        lds[xx * 136 + i] = f2bf(xin[(size_t)i * 4096 + xx] + off);
    }
    __syncthreads();
    for (int c = t; c < 1056; c += 256) {
        int e = c * 8, xx = e >> 7, i0 = e & 127;
        int4 v;
        if (xx == 0 || xx == 65) v = padvec;
        else v = *(const int4*)(lds + (xx - 1) * 136 + i0);
        *(int4*)(row + e) = v;
    }
}

// ------------------------------------------------- K3a: U_cat[h][k] bf16
__global__ __launch_bounds__(256) void k3a_ucat(
    const float* __restrict__ U, u16* __restrict__ Ucat) {
    int id = blockIdx.x * 256 + threadIdx.x;
    int h = id >> 8, k = id & 255;
    int s = k >> 4, q = k & 15;
    Ucat[id] = f2bf(U[((size_t)s * HD_ + h) * 16 + q]);
}

// ------------------------------------------------- K3v: Vt[w][k] f32 (transpose)
__global__ __launch_bounds__(256) void k3v_vt(
    const float* __restrict__ V, float* __restrict__ Vt) {
    int id = blockIdx.x * 256 + threadIdx.x;   // 98304
    int w = id >> 8, k = id & 255;
    Vt[id] = V[(size_t)k * WD_ + w];
}

// ---------------------- K4: gathered-space GEMM per (kh,kw) -> cw2 fragments
// G[bi][bj] = sum_k Ucat[bi*3+kh, k] * (Vt[bj*3+kw, k] * sc[b,k])
// cw2 layout: [b][khkw][i2(16)][o(256)][i8(8)] bf16, o=(bi&1)*128+bj, i=bi>>1
__global__ __launch_bounds__(256, 2) void k4_dw(
    const u16* __restrict__ Ucat, const float* __restrict__ Vt,
    const float* __restrict__ sc, const float* __restrict__ bias_dw,
    u16* __restrict__ cw2) {
    int mt = blockIdx.x, khkw = blockIdx.y, b = blockIdx.z;
    int kh = khkw / 3, kw = khkw - kh * 3;
    int t = threadIdx.x;
    __shared__ __align__(16) u16 Al[128 * 40];
    __shared__ __align__(16) u16 Bl[128 * 40];
    __shared__ float scl[256];
    scl[t] = sc[b * 256 + t];
    f32x4 acc[4][4] = {};
    int wid = t >> 6, l = t & 63;
    int wm = wid >> 1, wn = wid & 1;
    int lr = l & 15, lg = l >> 4;
    int bi0 = mt * 128;
    for (int kc = 0; kc < 8; ++kc) {
        __syncthreads();
        #pragma unroll
        for (int it = 0; it < 2; ++it) {
            int cid = t + it * 256;
            int g = cid & 3, rr = cid >> 2;
            int4 v = *(const int4*)(Ucat + (size_t)((bi0 + rr) * 3 + kh) * 256 + kc * 32 + g * 8);
            *(int4*)(Al + rr * 40 + g * 8) = v;
        }
        #pragma unroll
        for (int it = 0; it < 4; ++it) {
            int cid = t + it * 256;            // 1024 float4 chunks
            int q = cid & 7, rr = cid >> 3;
            int kb = kc * 32 + q * 4;
            float4 v = *(const float4*)(Vt + (size_t)(rr * 3 + kw) * 256 + kb);
            ushort4 p;
            p.x = f2bf(v.x * scl[kb]);
            p.y = f2bf(v.y * scl[kb + 1]);
            p.z = f2bf(v.z * scl[kb + 2]);
            p.w = f2bf(v.w * scl[kb + 3]);
            *(ushort4*)(Bl + rr * 40 + q * 4) = p;
        }
        __syncthreads();
        short8 a[4];
        #pragma unroll
        for (int fm = 0; fm < 4; ++fm)
            a[fm] = *(const short8*)(Al + (wm * 64 + fm * 16 + lr) * 40 + lg * 8);
        #pragma unroll
        for (int fn = 0; fn < 4; ++fn) {
            short8 bb = *(const short8*)(Bl + (wn * 64 + fn * 16 + lr) * 40 + lg * 8);
            #pragma unroll
            for (int fm = 0; fm < 4; ++fm)
                acc[fm][fn] = __builtin_amdgcn_mfma_f32_16x16x32_bf16(a[fm], bb, acc[fm][fn], 0, 0, 0);
        }
    }
    // epilogue: packed 4B stores into contiguous 32KB cw2 region
    u16* cwb = cw2 + (size_t)b * 294912;
    #pragma unroll
    for (int fm = 0; fm < 4; ++fm) {
        int i2 = mt * 8 + wm * 4 + fm;
        int B0 = bi0 + wm * 64 + fm * 16 + lg * 4;   // even, multiple of 4
        #pragma unroll
        for (int fn = 0; fn < 4; ++fn) {
            int bjj = wn * 64 + fn * 16 + lr;
            int wcol = bjj * 3 + kw;
            // even-bi pair: j=0 (bi=B0), j=2 (bi=B0+2) -> o=bjj, i8=2lg,2lg+1
            float v0 = acc[fm][fn][0] + bias_dw[(B0 + 0) * 3 * 384 + kh * 384 + wcol];
            float v2 = acc[fm][fn][2] + bias_dw[(B0 + 2) * 3 * 384 + kh * 384 + wcol];
            unsigned pe = (unsigned)f2bf(v0) | ((unsigned)f2bf(v2) << 16);
            size_t base = ((size_t)(khkw * 16 + i2) * 256);
            *(unsigned*)(cwb + (base + bjj) * 8 + 2 * lg) = pe;
            // odd-bi pair: j=1,3 -> o=bjj+128, same i8 pair
            float v1 = acc[fm][fn][1] + bias_dw[(B0 + 1) * 3 * 384 + kh * 384 + wcol];
            float v3 = acc[fm][fn][3] + bias_dw[(B0 + 3) * 3 * 384 + kh * 384 + wcol];
            unsigned po = (unsigned)f2bf(v1) | ((unsigned)f2bf(v3) << 16);
            *(unsigned*)(cwb + (base + bjj + 128) * 8 + 2 * lg) = po;
        }
    }
}

// --------------------------------------------- K6: implicit-GEMM conv (MFMA)
// W fragments read directly from L2 (cw2), X staged in XOR-swizzled LDS.
__global__ __launch_bounds__(256, 2) void k6_conv(
    const u16* __restrict__ xp, const u16* __restrict__ cw2,
    const float* __restrict__ bias_conv, float* __restrict__ out) {
    int f = blockIdx.x;
    int xcd = f & 7, sub = f >> 3;
    int b = xcd * 4 + (sub >> 5);      // all 32 pixel-blocks of b on one XCD
    int nt = sub & 31;
    int t = threadIdx.x;
    int y0 = nt * 2;
    __shared__ __align__(16) u16 Xl[4 * 66 * 32];
    f32x4 acc[4][8] = {};
    int wid = t >> 6, l = t & 63, lr = l & 15, lg = l >> 4;
    const u16* xpb = xp + (size_t)b * (66 * 66 * 128);
    const u16* cwb = cw2 + (size_t)b * 294912;
    for (int ic = 0; ic < 4; ++ic) {
        __syncthreads();
        #pragma unroll
        for (int it = 0; it < 5; ++it) {
            int cid = t + it * 256;
            if (cid < 1056) {
                int row = cid / 264, rem = cid - row * 264;
                int col = rem >> 2, g = rem & 3;
                int4 v = *(const int4*)(xpb + ((size_t)((y0 + row) * 66 + col)) * 128 + ic * 32 + g * 8);
                int chunk = (((row * 66 + col) * 4 + g) ^ (col & 7));
                *(int4*)((char*)Xl + chunk * 16) = v;
            }
        }
        __syncthreads();
        #pragma unroll
        for (int khkw = 0; khkw < 9; ++khkw) {
            const int kh = khkw / 3, kw = khkw - kh * 3;
            short8 a[4];
            #pragma unroll
            for (int fm = 0; fm < 4; ++fm) {
                int o = wid * 64 + fm * 16 + lr;
                a[fm] = *(const short8*)(cwb + ((size_t)((khkw * 16 + ic * 4 + lg) * 256 + o) << 3));
            }
            __builtin_amdgcn_s_setprio(1);
            #pragma unroll
            for (int fn = 0; fn < 8; ++fn) {
                int r = (fn >> 2) + kh, c = (fn & 3) * 16 + lr + kw;
                int chunk = (((r * 66 + c) * 4 + lg) ^ (c & 7));
                short8 bb = *(const short8*)((const char*)Xl + chunk * 16);
                #pragma unroll
                for (int fm = 0; fm < 4; ++fm)
                    acc[fm][fn] = __builtin_amdgcn_mfma_f32_16x16x32_bf16(a[fm], bb, acc[fm][fn], 0, 0, 0);
            }
            __builtin_amdgcn_s_setprio(0);
        }
    }
    #pragma unroll
    for (int fm = 0; fm < 4; ++fm)
        #pragma unroll
        for (int fn = 0; fn < 8; ++fn) {
            int y = y0 + (fn >> 2);
            int xb = (fn & 3) * 16 + lr;
            #pragma unroll
            for (int j = 0; j < 4; ++j) {
                int o = wid * 64 + fm * 16 + lg * 4 + j;
                out[(((size_t)b * 256 + o) * 64 + y) * 64 + xb] = acc[fm][fn][j] + bias_conv[o];
            }
        }
}

extern "C" void kernel_launch(void* const* d_in, const int* in_sizes, int n_in,
                              void* d_out, int out_size, void* d_ws, size_t ws_size,
                              hipStream_t stream) {
    const float* x     = (const float*)d_in[0];
    const float* ctx   = (const float*)d_in[1];
    const float* Wm    = (const float*)d_in[2];
    const float* z     = (const float*)d_in[3];
    const float* Are   = (const float*)d_in[4];
    const float* Aim   = (const float*)d_in[5];
    const float* U     = (const float*)d_in[6];
    const float* V     = (const float*)d_in[7];
    const float* bdw   = (const float*)d_in[8];
    const float* bconv = (const float*)d_in[9];
    const float* padv  = (const float*)d_in[10];
    const float* offv  = (const float*)d_in[11];
    float* out = (float*)d_out;
    char* ws = (char*)d_ws;

    u16*   xp   = (u16*)(ws);                 // 35,684,352 B
    u16*   cw2  = (u16*)(ws + 35684352);      // 18,874,368 B
    u16*   Ucat = (u16*)(ws + 54558720);      //    393,216 B
    float* Vt   = (float*)(ws + 54951936);    //    393,216 B
    float* sc   = (float*)(ws + 55345152);    //     32,768 B  (total ~55.4 MB)

    k1_mobius<<<32, 256, 0, stream>>>(ctx, Wm, z, Are, Aim, sc);
    k2_pad<<<dim3(66, 32), 256, 0, stream>>>(x, padv, offv, xp);
    k3a_ucat<<<768, 256, 0, stream>>>(U, Ucat);
    k3v_vt<<<384, 256, 0, stream>>>(V, Vt);
    k4_dw<<<dim3(2, 9, 32), 256, 0, stream>>>(Ucat, Vt, sc, bdw, cw2);
    k6_conv<<<1024, 256, 0, stream>>>(xp, cw2, bconv, out);
}

// Round 3
// 349.956 us; speedup vs baseline: 1.2372x; 1.0525x over previous
//
#include <hip/hip_runtime.h>
#include <hip/hip_bf16.h>

typedef __attribute__((ext_vector_type(8))) short short8;
typedef __attribute__((ext_vector_type(4))) float f32x4;
typedef unsigned short u16;

#define B_      32
#define IC_     128
#define OC_     256
#define HD_     768
#define WD_     384
#define CTX_    256

static __device__ __forceinline__ u16 f2bf(float f) {
    union { float f; unsigned u; } x; x.f = f;
    unsigned r = x.u + 0x7FFFu + ((x.u >> 16) & 1u);
    return (u16)(r >> 16);
}

static __device__ __forceinline__ void glds16(const void* g, void* l) {
    __builtin_amdgcn_global_load_lds(
        (const __attribute__((address_space(1))) unsigned*)g,
        (__attribute__((address_space(3))) unsigned*)l, 16, 0, 0);
}

#define BARRIER() asm volatile("s_barrier" ::: "memory")
template <int N> static __device__ __forceinline__ void waitvm() {
    if constexpr (N == 0)      asm volatile("s_waitcnt vmcnt(0)" ::: "memory");
    else if constexpr (N == 4) asm volatile("s_waitcnt vmcnt(4)" ::: "memory");
    else if constexpr (N == 9) asm volatile("s_waitcnt vmcnt(9)" ::: "memory");
}

// ---------------------------------------------------------------- K1: mobius
__global__ __launch_bounds__(256) void k1_mobius(
    const float* __restrict__ ctx, const float* __restrict__ Wm,
    const float* __restrict__ z, const float* __restrict__ Are,
    const float* __restrict__ Aim, float* __restrict__ sc) {
    int b = blockIdx.x, t = threadIdx.x;
    __shared__ float lctx[CTX_];
    __shared__ float lwre[256], lwim[256];
    lctx[t] = ctx[b * CTX_ + t];
    __syncthreads();
    float m0=0,m1=0,m2=0,m3=0,m4=0,m5=0,m6=0,m7=0;
    const float4* wp4 = (const float4*)Wm + (size_t)t * 2;
    #pragma unroll 4
    for (int c = 0; c < CTX_; ++c) {
        float4 w0 = wp4[(size_t)c * 512];
        float4 w1 = wp4[(size_t)c * 512 + 1];
        float cv = lctx[c];
        m0 += cv*w0.x; m1 += cv*w0.y; m2 += cv*w0.z; m3 += cv*w0.w;
        m4 += cv*w1.x; m5 += cv*w1.y; m6 += cv*w1.z; m7 += cv*w1.w;
    }
    float zre = z[t*2], zim = z[t*2+1];
    float nre = m0*zre - m1*zim + m2;
    float nim = m0*zim + m1*zre + m3;
    float dre = m4*zre - m5*zim + m6;
    float dim_ = m4*zim + m5*zre + m7;
    float den2 = dre*dre + dim_*dim_ + 1e-3f;
    lwre[t] = (nre*dre + nim*dim_) / den2;
    lwim[t] = (nim*dre - nre*dim_) / den2;
    __syncthreads();
    int s = t >> 4, q = t & 15;
    float acc = 0.f;
    #pragma unroll
    for (int r2 = 0; r2 < 16; ++r2) {
        int sr = s*16 + r2;
        acc += lwre[sr]*Are[sr*16 + q] + lwim[sr]*Aim[sr*16 + q];
    }
    sc[b*256 + t] = acc;
}

// ---------------------------------------------------- K2: padded bf16 image
__global__ __launch_bounds__(256) void k2_pad(
    const float* __restrict__ x, const float* __restrict__ padv,
    const float* __restrict__ offv, u16* __restrict__ xp) {
    int yy = blockIdx.x, b = blockIdx.y, t = threadIdx.x;
    __shared__ u16 lds[64 * 136];
    float off = offv[0];
    u16 pb = f2bf(padv[0]);
    unsigned pp = (unsigned)pb | ((unsigned)pb << 16);
    int4 padvec = make_int4((int)pp, (int)pp, (int)pp, (int)pp);
    u16* row = xp + (size_t)(b * 66 + yy) * (66 * 128);
    if (yy == 0 || yy == 65) {
        for (int c = t; c < 1056; c += 256)
            *(int4*)(row + c * 8) = padvec;
        return;
    }
    int y = yy - 1;
    const float* xin = x + (size_t)b * 524288 + (size_t)y * 64;
    for (int id = t; id < 8192; id += 256) {
        int i = id >> 6, xx = id & 63;
        lds[xx * 136 + i] = f2bf(xin[(size_t)i * 4096 + xx] + off);
    }
    __syncthreads();
    for (int c = t; c < 1056; c += 256) {
        int e = c * 8, xx = e >> 7, i0 = e & 127;
        int4 v;
        if (xx == 0 || xx == 65) v = padvec;
        else v = *(const int4*)(lds + (xx - 1) * 136 + i0);
        *(int4*)(row + e) = v;
    }
}

// ---------------------------------------- K3: Ucat bf16 + Vt f32 (merged)
__global__ __launch_bounds__(256) void k3_prep(
    const float* __restrict__ U, const float* __restrict__ V,
    u16* __restrict__ Ucat, float* __restrict__ Vt) {
    int id = blockIdx.x * 256 + threadIdx.x;
    if (id < 768 * 256) {
        int h = id >> 8, k = id & 255;
        int s = k >> 4, q = k & 15;
        Ucat[id] = f2bf(U[((size_t)s * HD_ + h) * 16 + q]);
    } else {
        int id2 = id - 768 * 256;
        int w = id2 >> 8, k = id2 & 255;
        Vt[id2] = V[(size_t)k * WD_ + w];
    }
}

// ---------------------- K4: gathered-space GEMM per (kh,kw) -> cw2 fragments
// cw2 layout: [b][khkw][i2(16)][o(256)][i8(8)] bf16, o=(bi&1)*128+bj, i=bi>>1
__global__ __launch_bounds__(256, 2) void k4_dw(
    const u16* __restrict__ Ucat, const float* __restrict__ Vt,
    const float* __restrict__ sc, const float* __restrict__ bias_dw,
    u16* __restrict__ cw2) {
    int mt = blockIdx.x, khkw = blockIdx.y, b = blockIdx.z;
    int kh = khkw / 3, kw = khkw - kh * 3;
    int t = threadIdx.x;
    __shared__ __align__(16) u16 Al[128 * 40];
    __shared__ __align__(16) u16 Bl[128 * 40];
    __shared__ float scl[256];
    scl[t] = sc[b * 256 + t];
    f32x4 acc[4][4] = {};
    int wid = t >> 6, l = t & 63;
    int wm = wid >> 1, wn = wid & 1;
    int lr = l & 15, lg = l >> 4;
    int bi0 = mt * 128;
    for (int kc = 0; kc < 8; ++kc) {
        __syncthreads();
        #pragma unroll
        for (int it = 0; it < 2; ++it) {
            int cid = t + it * 256;
            int g = cid & 3, rr = cid >> 2;
            int4 v = *(const int4*)(Ucat + (size_t)((bi0 + rr) * 3 + kh) * 256 + kc * 32 + g * 8);
            *(int4*)(Al + rr * 40 + g * 8) = v;
        }
        #pragma unroll
        for (int it = 0; it < 4; ++it) {
            int cid = t + it * 256;
            int q = cid & 7, rr = cid >> 3;
            int kb = kc * 32 + q * 4;
            float4 v = *(const float4*)(Vt + (size_t)(rr * 3 + kw) * 256 + kb);
            ushort4 p;
            p.x = f2bf(v.x * scl[kb]);
            p.y = f2bf(v.y * scl[kb + 1]);
            p.z = f2bf(v.z * scl[kb + 2]);
            p.w = f2bf(v.w * scl[kb + 3]);
            *(ushort4*)(Bl + rr * 40 + q * 4) = p;
        }
        __syncthreads();
        short8 a[4];
        #pragma unroll
        for (int fm = 0; fm < 4; ++fm)
            a[fm] = *(const short8*)(Al + (wm * 64 + fm * 16 + lr) * 40 + lg * 8);
        #pragma unroll
        for (int fn = 0; fn < 4; ++fn) {
            short8 bb = *(const short8*)(Bl + (wn * 64 + fn * 16 + lr) * 40 + lg * 8);
            #pragma unroll
            for (int fm = 0; fm < 4; ++fm)
                acc[fm][fn] = __builtin_amdgcn_mfma_f32_16x16x32_bf16(a[fm], bb, acc[fm][fn], 0, 0, 0);
        }
    }
    u16* cwb = cw2 + (size_t)b * 294912;
    #pragma unroll
    for (int fm = 0; fm < 4; ++fm) {
        int i2 = mt * 8 + wm * 4 + fm;
        int B0 = bi0 + wm * 64 + fm * 16 + lg * 4;
        #pragma unroll
        for (int fn = 0; fn < 4; ++fn) {
            int bjj = wn * 64 + fn * 16 + lr;
            int wcol = bjj * 3 + kw;
            float v0 = acc[fm][fn][0] + bias_dw[(B0 + 0) * 3 * 384 + kh * 384 + wcol];
            float v2 = acc[fm][fn][2] + bias_dw[(B0 + 2) * 3 * 384 + kh * 384 + wcol];
            unsigned pe = (unsigned)f2bf(v0) | ((unsigned)f2bf(v2) << 16);
            size_t base = ((size_t)(khkw * 16 + i2) * 256);
            *(unsigned*)(cwb + (base + bjj) * 8 + 2 * lg) = pe;
            float v1 = acc[fm][fn][1] + bias_dw[(B0 + 1) * 3 * 384 + kh * 384 + wcol];
            float v3 = acc[fm][fn][3] + bias_dw[(B0 + 3) * 3 * 384 + kh * 384 + wcol];
            unsigned po = (unsigned)f2bf(v1) | ((unsigned)f2bf(v3) << 16);
            *(unsigned*)(cwb + (base + bjj + 128) * 8 + 2 * lg) = po;
        }
    }
}

// --------------------------------------------- K6: pipelined implicit GEMM
// W double-buffered LDS (global_load_lds, prefetch 1 step), X double-buffered
// with XOR-swizzled global source, counted vmcnt + raw barriers, setprio.
static __device__ __forceinline__ void stage_W(
    const u16* cwb, int khkw, int ic, u16* wl, int t) {
    const u16* slice = cwb + ((size_t)(khkw * 16 + ic * 4) * 256) * 8;
    int wbase = t & ~63;
    #pragma unroll
    for (int it = 0; it < 4; ++it) {
        int cid = it * 256 + t;
        glds16(slice + (size_t)cid * 8, wl + (size_t)(it * 256 + wbase) * 8);
    }
}

static __device__ __forceinline__ void stage_X(
    const u16* xpb, int ic, int y0, u16* xl, int t) {
    int wbase = t & ~63;
    #pragma unroll
    for (int it = 0; it < 5; ++it) {
        int cid = it * 256 + t;
        const u16* g;
        if (cid < 1056) {
            int n = cid ^ ((cid >> 3) & 7);
            int gq = (n >= 792) ? 3 : (n >= 528) ? 2 : (n >= 264) ? 1 : 0;
            int rem = n - gq * 264;
            int r = (rem * 993) >> 16;
            int c = rem - r * 66;
            g = xpb + ((size_t)(y0 + r) * 66 + c) * 128 + ic * 32 + gq * 8;
        } else {
            g = xpb;  // dummy load into pad region
        }
        glds16(g, xl + (size_t)(it * 256 + wbase) * 8);
    }
}

__global__ __launch_bounds__(256, 2) void k6_conv(
    const u16* __restrict__ xp, const u16* __restrict__ cw2,
    const float* __restrict__ bias_conv, float* __restrict__ out) {
    int f = blockIdx.x;
    int xcd = f & 7, sub = f >> 3;
    int b = xcd * 4 + (sub >> 5);
    int nt = sub & 31;
    int t = threadIdx.x;
    int y0 = nt * 2;
    __shared__ __align__(16) u16 Wl[2][1024 * 8];   // 2 x 16 KiB
    __shared__ __align__(16) u16 Xl[2][1280 * 8];   // 2 x 20 KiB (1056 + pad)
    f32x4 acc[4][8] = {};
    int wid = t >> 6, l = t & 63, lr = l & 15, lg = l >> 4;
    const u16* xpb = xp + (size_t)b * (66 * 66 * 128);
    const u16* cwb = cw2 + (size_t)b * 294912;

    // prologue
    stage_X(xpb, 0, y0, Xl[0], t);
    stage_W(cwb, 0, 0, Wl[0], t);
    waitvm<0>();
    BARRIER();

    #pragma unroll
    for (int ic = 0; ic < 4; ++ic) {
        #pragma unroll
        for (int khkw = 0; khkw < 9; ++khkw) {
            const int s = ic * 9 + khkw;
            const int kh = khkw / 3, kw = khkw - kh * 3;
            // prefetch
            if (khkw == 8 && ic < 3)
                stage_X(xpb, ic + 1, y0, Xl[(ic + 1) & 1], t);
            if (s + 1 < 36) {
                const int nk = (s + 1) % 9, nic = (s + 1) / 9;
                stage_W(cwb, nk, nic, Wl[(s + 1) & 1], t);
            }
            if (s == 35) waitvm<0>();
            else if (khkw == 8) waitvm<9>();
            else waitvm<4>();
            BARRIER();
            const u16* wl = Wl[s & 1];
            const u16* xl = Xl[ic & 1];
            short8 a[4];
            #pragma unroll
            for (int fm = 0; fm < 4; ++fm) {
                int o = wid * 64 + fm * 16 + lr;
                a[fm] = *(const short8*)(wl + (size_t)(lg * 256 + o) * 8);
            }
            __builtin_amdgcn_s_setprio(1);
            #pragma unroll
            for (int fn = 0; fn < 8; ++fn) {
                int r = (fn >> 2) + kh, c = (fn & 3) * 16 + lr + kw;
                int n = lg * 264 + r * 66 + c;
                int m = n ^ ((n >> 3) & 7);
                short8 bb = *(const short8*)(xl + (size_t)m * 8);
                #pragma unroll
                for (int fm = 0; fm < 4; ++fm)
                    acc[fm][fn] = __builtin_amdgcn_mfma_f32_16x16x32_bf16(a[fm], bb, acc[fm][fn], 0, 0, 0);
            }
            __builtin_amdgcn_s_setprio(0);
            if (s != 35) BARRIER();
        }
    }
    #pragma unroll
    for (int fm = 0; fm < 4; ++fm)
        #pragma unroll
        for (int fn = 0; fn < 8; ++fn) {
            int y = y0 + (fn >> 2);
            int xb = (fn & 3) * 16 + lr;
            #pragma unroll
            for (int j = 0; j < 4; ++j) {
                int o = wid * 64 + fm * 16 + lg * 4 + j;
                out[(((size_t)b * 256 + o) * 64 + y) * 64 + xb] = acc[fm][fn][j] + bias_conv[o];
            }
        }
}

extern "C" void kernel_launch(void* const* d_in, const int* in_sizes, int n_in,
                              void* d_out, int out_size, void* d_ws, size_t ws_size,
                              hipStream_t stream) {
    const float* x     = (const float*)d_in[0];
    const float* ctx   = (const float*)d_in[1];
    const float* Wm    = (const float*)d_in[2];
    const float* z     = (const float*)d_in[3];
    const float* Are   = (const float*)d_in[4];
    const float* Aim   = (const float*)d_in[5];
    const float* U     = (const float*)d_in[6];
    const float* V     = (const float*)d_in[7];
    const float* bdw   = (const float*)d_in[8];
    const float* bconv = (const float*)d_in[9];
    const float* padv  = (const float*)d_in[10];
    const float* offv  = (const float*)d_in[11];
    float* out = (float*)d_out;
    char* ws = (char*)d_ws;

    u16*   xp   = (u16*)(ws);                 // 35,684,352 B
    u16*   cw2  = (u16*)(ws + 35684352);      // 18,874,368 B
    u16*   Ucat = (u16*)(ws + 54558720);      //    393,216 B
    float* Vt   = (float*)(ws + 54951936);    //    393,216 B
    float* sc   = (float*)(ws + 55345152);    //     32,768 B

    k1_mobius<<<32, 256, 0, stream>>>(ctx, Wm, z, Are, Aim, sc);
    k2_pad<<<dim3(66, 32), 256, 0, stream>>>(x, padv, offv, xp);
    k3_prep<<<1152, 256, 0, stream>>>(U, V, Ucat, Vt);
    k4_dw<<<dim3(2, 9, 32), 256, 0, stream>>>(Ucat, Vt, sc, bdw, cw2);
    k6_conv<<<1024, 256, 0, stream>>>(xp, cw2, bconv, out);
}

// Round 4
// 331.353 us; speedup vs baseline: 1.3067x; 1.0561x over previous
//
#include <hip/hip_runtime.h>
#include <hip/hip_bf16.h>

typedef __attribute__((ext_vector_type(8))) short short8;
typedef __attribute__((ext_vector_type(4))) float f32x4;
typedef unsigned short u16;

#define B_      32
#define IC_     128
#define OC_     256
#define HD_     768
#define WD_     384
#define CTX_    256

static __device__ __forceinline__ u16 f2bf(float f) {
    union { float f; unsigned u; } x; x.f = f;
    unsigned r = x.u + 0x7FFFu + ((x.u >> 16) & 1u);
    return (u16)(r >> 16);
}

static __device__ __forceinline__ void glds16(const void* g, void* l) {
    __builtin_amdgcn_global_load_lds(
        (const __attribute__((address_space(1))) unsigned*)g,
        (__attribute__((address_space(3))) unsigned*)l, 16, 0, 0);
}

#define BARRIER() asm volatile("s_barrier" ::: "memory")
static __device__ __forceinline__ void waitvm0() {
    asm volatile("s_waitcnt vmcnt(0)" ::: "memory");
}

// ================= k_pre: mobius (blocks 0..31) + pad (32..2143) + prep =====
__global__ __launch_bounds__(256) void k_pre(
    const float* __restrict__ ctx, const float* __restrict__ Wm,
    const float* __restrict__ z, const float* __restrict__ Are,
    const float* __restrict__ Aim, const float* __restrict__ x,
    const float* __restrict__ padv, const float* __restrict__ offv,
    const float* __restrict__ U, const float* __restrict__ V,
    float* __restrict__ sc, u16* __restrict__ xp,
    u16* __restrict__ Ucat, float* __restrict__ Vt) {
    int bid = blockIdx.x, t = threadIdx.x;
    if (bid < 32) {
        // ---- mobius
        int b = bid;
        __shared__ float lctx[CTX_];
        __shared__ float lwre[256], lwim[256];
        lctx[t] = ctx[b * CTX_ + t];
        __syncthreads();
        float m0=0,m1=0,m2=0,m3=0,m4=0,m5=0,m6=0,m7=0;
        const float4* wp4 = (const float4*)Wm + (size_t)t * 2;
        #pragma unroll 4
        for (int c = 0; c < CTX_; ++c) {
            float4 w0 = wp4[(size_t)c * 512];
            float4 w1 = wp4[(size_t)c * 512 + 1];
            float cv = lctx[c];
            m0 += cv*w0.x; m1 += cv*w0.y; m2 += cv*w0.z; m3 += cv*w0.w;
            m4 += cv*w1.x; m5 += cv*w1.y; m6 += cv*w1.z; m7 += cv*w1.w;
        }
        float zre = z[t*2], zim = z[t*2+1];
        float nre = m0*zre - m1*zim + m2;
        float nim = m0*zim + m1*zre + m3;
        float dre = m4*zre - m5*zim + m6;
        float dim_ = m4*zim + m5*zre + m7;
        float den2 = dre*dre + dim_*dim_ + 1e-3f;
        lwre[t] = (nre*dre + nim*dim_) / den2;
        lwim[t] = (nim*dre - nre*dim_) / den2;
        __syncthreads();
        int s = t >> 4, q = t & 15;
        float acc = 0.f;
        #pragma unroll
        for (int r2 = 0; r2 < 16; ++r2) {
            int sr = s*16 + r2;
            acc += lwre[sr]*Are[sr*16 + q] + lwim[sr]*Aim[sr*16 + q];
        }
        sc[b*256 + t] = acc;
    } else if (bid < 2144) {
        // ---- pad: xp[b][yy][xx][i] channel-last bf16
        int pb_ = bid - 32;
        int yy = pb_ % 66, b = pb_ / 66;
        __shared__ u16 lds[64 * 136];
        float off = offv[0];
        u16 pb = f2bf(padv[0]);
        unsigned pp = (unsigned)pb | ((unsigned)pb << 16);
        int4 padvec = make_int4((int)pp, (int)pp, (int)pp, (int)pp);
        u16* row = xp + (size_t)(b * 66 + yy) * (66 * 128);
        if (yy == 0 || yy == 65) {
            for (int c = t; c < 1056; c += 256)
                *(int4*)(row + c * 8) = padvec;
            return;
        }
        int y = yy - 1;
        const float* xin = x + (size_t)b * 524288 + (size_t)y * 64;
        for (int id = t; id < 8192; id += 256) {
            int i = id >> 6, xx = id & 63;
            lds[xx * 136 + i] = f2bf(xin[(size_t)i * 4096 + xx] + off);
        }
        __syncthreads();
        for (int c = t; c < 1056; c += 256) {
            int e = c * 8, xx = e >> 7, i0 = e & 127;
            int4 v;
            if (xx == 0 || xx == 65) v = padvec;
            else v = *(const int4*)(lds + (xx - 1) * 136 + i0);
            *(int4*)(row + e) = v;
        }
    } else {
        // ---- prep: Ucat bf16 + Vt f32
        int id = (bid - 2144) * 256 + t;
        if (id < 768 * 256) {
            int h = id >> 8, k = id & 255;
            int s = k >> 4, q = k & 15;
            Ucat[id] = f2bf(U[((size_t)s * HD_ + h) * 16 + q]);
        } else {
            int id2 = id - 768 * 256;
            int w = id2 >> 8, k = id2 & 255;
            Vt[id2] = V[(size_t)k * WD_ + w];
        }
    }
}

// ---------------------- K4: gathered-space GEMM per (kh,kw) -> cw2 fragments
// cw2 layout: [b][khkw][i2(16)][o(256)][i8(8)] bf16, o=(bi&1)*128+bj, i=bi>>1
__global__ __launch_bounds__(256, 2) void k4_dw(
    const u16* __restrict__ Ucat, const float* __restrict__ Vt,
    const float* __restrict__ sc, const float* __restrict__ bias_dw,
    u16* __restrict__ cw2) {
    int mt = blockIdx.x, khkw = blockIdx.y, b = blockIdx.z;
    int kh = khkw / 3, kw = khkw - kh * 3;
    int t = threadIdx.x;
    __shared__ __align__(16) u16 Al[128 * 40];
    __shared__ __align__(16) u16 Bl[128 * 40];
    __shared__ float scl[256];
    scl[t] = sc[b * 256 + t];
    f32x4 acc[4][4] = {};
    int wid = t >> 6, l = t & 63;
    int wm = wid >> 1, wn = wid & 1;
    int lr = l & 15, lg = l >> 4;
    int bi0 = mt * 128;
    for (int kc = 0; kc < 8; ++kc) {
        __syncthreads();
        #pragma unroll
        for (int it = 0; it < 2; ++it) {
            int cid = t + it * 256;
            int g = cid & 3, rr = cid >> 2;
            int4 v = *(const int4*)(Ucat + (size_t)((bi0 + rr) * 3 + kh) * 256 + kc * 32 + g * 8);
            *(int4*)(Al + rr * 40 + g * 8) = v;
        }
        #pragma unroll
        for (int it = 0; it < 4; ++it) {
            int cid = t + it * 256;
            int q = cid & 7, rr = cid >> 3;
            int kb = kc * 32 + q * 4;
            float4 v = *(const float4*)(Vt + (size_t)(rr * 3 + kw) * 256 + kb);
            ushort4 p;
            p.x = f2bf(v.x * scl[kb]);
            p.y = f2bf(v.y * scl[kb + 1]);
            p.z = f2bf(v.z * scl[kb + 2]);
            p.w = f2bf(v.w * scl[kb + 3]);
            *(ushort4*)(Bl + rr * 40 + q * 4) = p;
        }
        __syncthreads();
        short8 a[4];
        #pragma unroll
        for (int fm = 0; fm < 4; ++fm)
            a[fm] = *(const short8*)(Al + (wm * 64 + fm * 16 + lr) * 40 + lg * 8);
        #pragma unroll
        for (int fn = 0; fn < 4; ++fn) {
            short8 bb = *(const short8*)(Bl + (wn * 64 + fn * 16 + lr) * 40 + lg * 8);
            #pragma unroll
            for (int fm = 0; fm < 4; ++fm)
                acc[fm][fn] = __builtin_amdgcn_mfma_f32_16x16x32_bf16(a[fm], bb, acc[fm][fn], 0, 0, 0);
        }
    }
    u16* cwb = cw2 + (size_t)b * 294912;
    #pragma unroll
    for (int fm = 0; fm < 4; ++fm) {
        int i2 = mt * 8 + wm * 4 + fm;
        int B0 = bi0 + wm * 64 + fm * 16 + lg * 4;
        #pragma unroll
        for (int fn = 0; fn < 4; ++fn) {
            int bjj = wn * 64 + fn * 16 + lr;
            int wcol = bjj * 3 + kw;
            float v0 = acc[fm][fn][0] + bias_dw[(B0 + 0) * 3 * 384 + kh * 384 + wcol];
            float v2 = acc[fm][fn][2] + bias_dw[(B0 + 2) * 3 * 384 + kh * 384 + wcol];
            unsigned pe = (unsigned)f2bf(v0) | ((unsigned)f2bf(v2) << 16);
            size_t base = ((size_t)(khkw * 16 + i2) * 256);
            *(unsigned*)(cwb + (base + bjj) * 8 + 2 * lg) = pe;
            float v1 = acc[fm][fn][1] + bias_dw[(B0 + 1) * 3 * 384 + kh * 384 + wcol];
            float v3 = acc[fm][fn][3] + bias_dw[(B0 + 3) * 3 * 384 + kh * 384 + wcol];
            unsigned po = (unsigned)f2bf(v1) | ((unsigned)f2bf(v3) << 16);
            *(unsigned*)(cwb + (base + bjj + 128) * 8 + 2 * lg) = po;
        }
    }
}

// --------------------------------------------- K6: implicit GEMM, W in regs
// X: LDS double-buffer via global_load_lds, staged once per ic (9-step reuse),
// only ONE vmcnt(0)+barrier per ic. W: L2->VGPR, 2-step software prefetch.
static __device__ __forceinline__ void stage_X(
    const u16* xpb, int ic, int y0, u16* xl, int t) {
    int wbase = t & ~63;
    #pragma unroll
    for (int it = 0; it < 5; ++it) {
        int cid = it * 256 + t;
        const u16* g;
        if (cid < 1056) {
            int n = cid ^ ((cid >> 3) & 7);
            int gq = (n >= 792) ? 3 : (n >= 528) ? 2 : (n >= 264) ? 1 : 0;
            int rem = n - gq * 264;
            int r = (rem * 993) >> 16;
            int c = rem - r * 66;
            g = xpb + ((size_t)(y0 + r) * 66 + c) * 128 + ic * 32 + gq * 8;
        } else {
            g = xpb;  // dummy load into pad region
        }
        glds16(g, xl + (size_t)(it * 256 + wbase) * 8);
    }
}

__global__ __launch_bounds__(256, 2) void k6_conv(
    const u16* __restrict__ xp, const u16* __restrict__ cw2,
    const float* __restrict__ bias_conv, float* __restrict__ out) {
    int f = blockIdx.x;
    int xcd = f & 7, sub = f >> 3;
    int b = xcd * 4 + (sub >> 5);
    int nt = sub & 31;
    int t = threadIdx.x;
    int y0 = nt * 2;
    __shared__ __align__(16) u16 Xl[2][1280 * 8];   // 2 x 20 KiB
    f32x4 acc[4][8] = {};
    int wid = t >> 6, l = t & 63, lr = l & 15, lg = l >> 4;
    const u16* xpb = xp + (size_t)b * (66 * 66 * 128);
    const u16* cwb = cw2 + (size_t)b * 294912;
    // per-lane W fragment base: frag(s, fm) at wbase + ((khkw*16+ic*4)*256 + fm*16)*8
    const u16* wbase = cwb + (size_t)((lg * 256) + wid * 64 + lr) * 8;

    short8 wreg[2][4];
    stage_X(xpb, 0, y0, Xl[0], t);
    #pragma unroll
    for (int fm = 0; fm < 4; ++fm)
        wreg[0][fm] = *(const short8*)(wbase + ((size_t)(0 * 16) * 256 + fm * 16) * 8);
    #pragma unroll
    for (int fm = 0; fm < 4; ++fm)
        wreg[1][fm] = *(const short8*)(wbase + ((size_t)(1 * 16) * 256 + fm * 16) * 8);

    #pragma unroll
    for (int ic = 0; ic < 4; ++ic) {
        #pragma unroll
        for (int khkw = 0; khkw < 9; ++khkw) {
            const int s = ic * 9 + khkw;
            const int kh = khkw / 3, kw = khkw - kh * 3;
            if (khkw == 0) {
                waitvm0();                      // own X glds (and W regs) drained
                __builtin_amdgcn_sched_barrier(0);
                BARRIER();                      // all waves' X staged
                if (ic < 3) stage_X(xpb, ic + 1, y0, Xl[(ic + 1) & 1], t);
            }
            const u16* xl = Xl[ic & 1];
            __builtin_amdgcn_s_setprio(1);
            #pragma unroll
            for (int fn = 0; fn < 8; ++fn) {
                int r = (fn >> 2) + kh, c = (fn & 3) * 16 + lr + kw;
                int n = lg * 264 + r * 66 + c;
                int m = n ^ ((n >> 3) & 7);
                short8 bb = *(const short8*)(xl + (size_t)m * 8);
                #pragma unroll
                for (int fm = 0; fm < 4; ++fm)
                    acc[fm][fn] = __builtin_amdgcn_mfma_f32_16x16x32_bf16(wreg[s & 1][fm], bb, acc[fm][fn], 0, 0, 0);
            }
            __builtin_amdgcn_s_setprio(0);
            if (s + 2 < 36) {
                const int s2 = s + 2, nic = s2 / 9, nk = s2 % 9;
                #pragma unroll
                for (int fm = 0; fm < 4; ++fm)
                    wreg[s & 1][fm] = *(const short8*)(wbase + ((size_t)(nk * 16 + nic * 4) * 256 + fm * 16) * 8);
            }
        }
    }
    #pragma unroll
    for (int fm = 0; fm < 4; ++fm)
        #pragma unroll
        for (int fn = 0; fn < 8; ++fn) {
            int y = y0 + (fn >> 2);
            int xb = (fn & 3) * 16 + lr;
            #pragma unroll
            for (int j = 0; j < 4; ++j) {
                int o = wid * 64 + fm * 16 + lg * 4 + j;
                out[(((size_t)b * 256 + o) * 64 + y) * 64 + xb] = acc[fm][fn][j] + bias_conv[o];
            }
        }
}

extern "C" void kernel_launch(void* const* d_in, const int* in_sizes, int n_in,
                              void* d_out, int out_size, void* d_ws, size_t ws_size,
                              hipStream_t stream) {
    const float* x     = (const float*)d_in[0];
    const float* ctx   = (const float*)d_in[1];
    const float* Wm    = (const float*)d_in[2];
    const float* z     = (const float*)d_in[3];
    const float* Are   = (const float*)d_in[4];
    const float* Aim   = (const float*)d_in[5];
    const float* U     = (const float*)d_in[6];
    const float* V     = (const float*)d_in[7];
    const float* bdw   = (const float*)d_in[8];
    const float* bconv = (const float*)d_in[9];
    const float* padv  = (const float*)d_in[10];
    const float* offv  = (const float*)d_in[11];
    float* out = (float*)d_out;
    char* ws = (char*)d_ws;

    u16*   xp   = (u16*)(ws);                 // 35,684,352 B
    u16*   cw2  = (u16*)(ws + 35684352);      // 18,874,368 B
    u16*   Ucat = (u16*)(ws + 54558720);      //    393,216 B
    float* Vt   = (float*)(ws + 54951936);    //    393,216 B
    float* sc   = (float*)(ws + 55345152);    //     32,768 B

    k_pre<<<3296, 256, 0, stream>>>(ctx, Wm, z, Are, Aim, x, padv, offv, U, V,
                                    sc, xp, Ucat, Vt);
    k4_dw<<<dim3(2, 9, 32), 256, 0, stream>>>(Ucat, Vt, sc, bdw, cw2);
    k6_conv<<<1024, 256, 0, stream>>>(xp, cw2, bconv, out);
}